// Round 2
// baseline (1285.498 us; speedup 1.0000x reference)
//
#include <hip/hip_runtime.h>
#include <cstdint>
#include <cstddef>

// B=2, H=16, S=2048, D=64. fp32 inputs (Q,K,V), mask (int32/uint8 auto-detected),
// fp32 outputs: [context | attn_prob] concatenated.
//
// v2: two-pass flash structure, NO LDS tile, NO barriers.
//  - each WAVE owns 16 q-rows x full S; waves fully independent.
//  - Pass A: QK^T (swapped) + mask + exp -> rowsum only (2 shfl_xor reduce).
//  - Pass B: recompute QK^T + exp; write fp32 normalized prob; pack P->bf16;
//    ds_bpermute quad-exchange into PV A-frag layout; 4 PV MFMAs into regs.
//  - occupancy: no LDS, VGPR<=128 (__launch_bounds__(256,4)) -> 16 waves/CU
//    (vs 8 before). Kernel was latency-bound at 2 waves/SIMD.
#define S_LEN 2048
#define D_HEAD 64
#define NBH 32

typedef __attribute__((ext_vector_type(8))) short short8;
typedef __attribute__((ext_vector_type(8))) unsigned short ushort8;
typedef __attribute__((ext_vector_type(4))) unsigned int ui4;
typedef __attribute__((ext_vector_type(4))) float floatx4;

__device__ __forceinline__ unsigned short f2bf(float f){
  union { float f; unsigned int i; } v; v.f = f;
  unsigned int u = v.i;
  u += 0x7fffu + ((u >> 16) & 1u);     // RNE
  return (unsigned short)(u >> 16);
}
__device__ __forceinline__ unsigned int pk2bf(float lo, float hi){
  return ((unsigned int)f2bf(hi) << 16) | (unsigned int)f2bf(lo);
}

// ---- mask width detect: int32 0/1 -> every 4B word <= 1; uint8 0/1 -> words >1 whp.
__global__ void detect_mask_kernel(const unsigned int* __restrict__ m, int* __restrict__ flag){
  __shared__ int f;
  if (threadIdx.x == 0) f = 0;
  __syncthreads();
  if (m[threadIdx.x] > 1u) atomicOr(&f, 1);
  __syncthreads();
  if (threadIdx.x == 0) *flag = f;   // 0 = int32, 1 = uint8
}

// ---- K fp32 -> Kb bf16 (same layout). 8 elems/thread.
__global__ void convK_kernel(const float* __restrict__ K, unsigned short* __restrict__ Kb){
  const size_t i = ((size_t)blockIdx.x * 256 + threadIdx.x) * 8;
  floatx4 x0 = *(const floatx4*)(K + i);
  floatx4 x1 = *(const floatx4*)(K + i + 4);
  ushort8 o;
#pragma unroll
  for (int j = 0; j < 4; ++j){ o[j] = f2bf(x0[j]); o[4 + j] = f2bf(x1[j]); }
  *(ushort8*)(Kb + i) = o;
}

// ---- V fp32 -> Vt bf16 transposed: Vt[bh][n][k] (k contiguous for PV B-frags).
__global__ void vtrans_kernel(const float* __restrict__ V, unsigned short* __restrict__ Vt){
  const int bh = blockIdx.y;
  const int n  = threadIdx.x & 63;
  const int k0 = blockIdx.x * 32 + (threadIdx.x >> 6) * 8;
  const float* Vp = V + (size_t)bh * S_LEN * D_HEAD;
  ushort8 o;
#pragma unroll
  for (int i = 0; i < 8; ++i) o[i] = f2bf(Vp[(size_t)(k0 + i) * D_HEAD + n]);
  *(ushort8*)(Vt + (size_t)bh * D_HEAD * S_LEN + (size_t)n * S_LEN + k0) = o;
}

// SWAPPED QK^T: c = mfma(K_frag, Q_frag) -> C col=lane&15 = q-row,
// row=quad*4+reg = score-col (verified r1). Lane (r16,quad) owns q-row r16,
// score-cols {16t + quad*4 + i}.
//
// PV A-frag needs lane to hold P[r16][k = quad*8 + j] per 32-col chunk.
// Fixed bijection: dest (q,d) <- src lane q' = 2(q&1)+(d>>1),
//                  src packed-dword j = 2(q>>1)+(d&1).
// Implemented as 8 ds_bpermute + 4 cndmask per chunk.
__global__ __launch_bounds__(256, 4) void attn_kernel(
    const float* __restrict__ Q, const unsigned short* __restrict__ Kb,
    const void* __restrict__ maskp, const int* __restrict__ flag,
    const unsigned short* __restrict__ Vt,
    float* __restrict__ prob, float* __restrict__ ctx){

  // XCD-aware remap: hw dispatch is x-major linear, round-robin over 8 XCDs.
  // 1024 blocks = 8 XCD x (4 heads x 32 qb). K+V bf16 for 4 heads = 2MB -> L2-resident.
  const int lin  = blockIdx.y * gridDim.x + blockIdx.x;
  const int xcd  = lin & 7;
  const int sub  = lin >> 3;
  const int bh   = xcd * 4 + (sub & 3);
  const int qb   = sub >> 2;                  // 64-row block index

  const int wave = threadIdx.x >> 6;
  const int lane = threadIdx.x & 63;
  const int quad = lane >> 4;
  const int r16  = lane & 15;

  const int q0g = bh * S_LEN + qb * 64 + wave * 16;   // this wave's first row (flattened)

  // ---- Q fragments (held all kernel) ----
  const float* qrow = Q + (size_t)(q0g + r16) * D_HEAD + quad * 8;
  short8 a0, a1;
  {
    floatx4 x0 = *(const floatx4*)(qrow);
    floatx4 x1 = *(const floatx4*)(qrow + 4);
    floatx4 y0 = *(const floatx4*)(qrow + 32);
    floatx4 y1 = *(const floatx4*)(qrow + 36);
#pragma unroll
    for (int j = 0; j < 4; ++j){
      a0[j] = (short)f2bf(x0[j]); a0[4 + j] = (short)f2bf(x1[j]);
      a1[j] = (short)f2bf(y0[j]); a1[4 + j] = (short)f2bf(y1[j]);
    }
  }

  const bool mInt = (*flag) == 0;
  const unsigned int*  mI = (const unsigned int*)maskp + (size_t)(q0g + r16) * S_LEN;
  const unsigned char* mB = (const unsigned char*)maskp + (size_t)(q0g + r16) * S_LEN;
  const unsigned short* kbase = Kb + (size_t)bh * S_LEN * D_HEAD;

  // ---- Pass A: rowsum only ----
  float racc = 0.f;
#pragma unroll 2
  for (int t = 0; t < 128; ++t){
    const unsigned short* krow = kbase + (size_t)(t * 16 + r16) * D_HEAD + quad * 8;
    const short8 b0 = *(const short8*)(krow);
    const short8 b1 = *(const short8*)(krow + 32);
    unsigned int mm[4];
    if (mInt){
      const ui4 m4 = *(const ui4*)(mI + t * 16 + quad * 4);
#pragma unroll
      for (int i = 0; i < 4; ++i) mm[i] = m4[i];
    } else {
      const unsigned int mv = *(const unsigned int*)(mB + t * 16 + quad * 4);
#pragma unroll
      for (int i = 0; i < 4; ++i) mm[i] = (mv >> (8 * i)) & 0xffu;
    }
    floatx4 c = {0.f, 0.f, 0.f, 0.f};
    c = __builtin_amdgcn_mfma_f32_16x16x32_bf16(b0, a0, c, 0, 0, 0);
    c = __builtin_amdgcn_mfma_f32_16x16x32_bf16(b1, a1, c, 0, 0, 0);
#pragma unroll
    for (int i = 0; i < 4; ++i)
      racc += mm[i] ? 0.0f : __expf(c[i] * 0.125f);
  }
  // quads hold col-disjoint partials of row r16
  racc += __shfl_xor(racc, 16);
  racc += __shfl_xor(racc, 32);
  const float inv = (racc > 0.f) ? (1.0f / racc) : 0.0f;

  // ---- Pass B: recompute + prob store + PV ----
  float* prow = prob + (size_t)(q0g + r16) * S_LEN;
  const unsigned short* vbase = Vt + (size_t)bh * D_HEAD * S_LEN
                                   + (size_t)r16 * S_LEN + quad * 8;
  floatx4 cc0 = {0.f,0.f,0.f,0.f}, cc1 = {0.f,0.f,0.f,0.f};
  floatx4 cc2 = {0.f,0.f,0.f,0.f}, cc3 = {0.f,0.f,0.f,0.f};

  for (int u = 0; u < 64; ++u){
    // two QK tiles: score-cols [32u,32u+16) and [32u+16,32u+32)
    const unsigned short* krow = kbase + (size_t)(u * 32 + r16) * D_HEAD + quad * 8;
    const short8 b00 = *(const short8*)(krow);
    const short8 b01 = *(const short8*)(krow + 32);
    const short8 b10 = *(const short8*)(krow + 16 * D_HEAD);
    const short8 b11 = *(const short8*)(krow + 16 * D_HEAD + 32);
    unsigned int m0[4], m1[4];
    if (mInt){
      const ui4 w0 = *(const ui4*)(mI + u * 32 + quad * 4);
      const ui4 w1 = *(const ui4*)(mI + u * 32 + 16 + quad * 4);
#pragma unroll
      for (int i = 0; i < 4; ++i){ m0[i] = w0[i]; m1[i] = w1[i]; }
    } else {
      const unsigned int v0m = *(const unsigned int*)(mB + u * 32 + quad * 4);
      const unsigned int v1m = *(const unsigned int*)(mB + u * 32 + 16 + quad * 4);
#pragma unroll
      for (int i = 0; i < 4; ++i){
        m0[i] = (v0m >> (8 * i)) & 0xffu;
        m1[i] = (v1m >> (8 * i)) & 0xffu;
      }
    }
    floatx4 c0 = {0.f,0.f,0.f,0.f}, c1 = {0.f,0.f,0.f,0.f};
    c0 = __builtin_amdgcn_mfma_f32_16x16x32_bf16(b00, a0, c0, 0, 0, 0);
    c0 = __builtin_amdgcn_mfma_f32_16x16x32_bf16(b01, a1, c0, 0, 0, 0);
    c1 = __builtin_amdgcn_mfma_f32_16x16x32_bf16(b10, a0, c1, 0, 0, 0);
    c1 = __builtin_amdgcn_mfma_f32_16x16x32_bf16(b11, a1, c1, 0, 0, 0);

    float p0[4], p1[4];
#pragma unroll
    for (int i = 0; i < 4; ++i){
      p0[i] = m0[i] ? 0.0f : __expf(c0[i] * 0.125f);
      p1[i] = m1[i] ? 0.0f : __expf(c1[i] * 0.125f);
    }

    // prob: fp32-precise, 64B-line coalesced (quads cover 16 consecutive floats)
    floatx4 o0, o1;
#pragma unroll
    for (int i = 0; i < 4; ++i){ o0[i] = p0[i] * inv; o1[i] = p1[i] * inv; }
    *(floatx4*)(prow + u * 32 + quad * 4)      = o0;
    *(floatx4*)(prow + u * 32 + 16 + quad * 4) = o1;

    // pack P (unnormalized; bounded by exp(max score) ~ e^6, bf16-safe)
    const int pl0 = (int)pk2bf(p0[0], p0[1]);
    const int pl1 = (int)pk2bf(p0[2], p0[3]);
    const int pl2 = (int)pk2bf(p1[0], p1[1]);
    const int pl3 = (int)pk2bf(p1[2], p1[3]);

    // quad-exchange into A-frag layout (byte indices for ds_bpermute)
    const int idx0 = (r16 + ((quad & 1) << 5)) << 2;   // src lane r16 + 32*(quad&1)
    const int idx1 = idx0 + 64;                        // +16 lanes
    const int t0a = __builtin_amdgcn_ds_bpermute(idx0, pl0);
    const int t0b = __builtin_amdgcn_ds_bpermute(idx0, pl2);
    const int t1a = __builtin_amdgcn_ds_bpermute(idx0, pl1);
    const int t1b = __builtin_amdgcn_ds_bpermute(idx0, pl3);
    const int t2a = __builtin_amdgcn_ds_bpermute(idx1, pl0);
    const int t2b = __builtin_amdgcn_ds_bpermute(idx1, pl2);
    const int t3a = __builtin_amdgcn_ds_bpermute(idx1, pl1);
    const int t3b = __builtin_amdgcn_ds_bpermute(idx1, pl3);
    const bool hi = quad >= 2;
    union { int d[4]; short8 s; } af;
    af.d[0] = hi ? t0b : t0a;
    af.d[1] = hi ? t1b : t1a;
    af.d[2] = hi ? t2b : t2a;
    af.d[3] = hi ? t3b : t3a;

    // PV: 4 n-tiles of 16 ctx-cols
    const short8 v0 = *(const short8*)(vbase + u * 32);
    const short8 v1 = *(const short8*)(vbase + 16 * S_LEN + u * 32);
    const short8 v2 = *(const short8*)(vbase + 32 * S_LEN + u * 32);
    const short8 v3 = *(const short8*)(vbase + 48 * S_LEN + u * 32);
    cc0 = __builtin_amdgcn_mfma_f32_16x16x32_bf16(af.s, v0, cc0, 0, 0, 0);
    cc1 = __builtin_amdgcn_mfma_f32_16x16x32_bf16(af.s, v1, cc1, 0, 0, 0);
    cc2 = __builtin_amdgcn_mfma_f32_16x16x32_bf16(af.s, v2, cc2, 0, 0, 0);
    cc3 = __builtin_amdgcn_mfma_f32_16x16x32_bf16(af.s, v3, cc3, 0, 0, 0);
  }

  // ---- ctx store: lane (r16,quad) holds rows quad*4+i, cols {nt*16 + r16} ----
  float inv4[4];
#pragma unroll
  for (int i = 0; i < 4; ++i) inv4[i] = __shfl(inv, quad * 4 + i, 64);
#pragma unroll
  for (int i = 0; i < 4; ++i){
    float* cr = ctx + (size_t)(q0g + quad * 4 + i) * D_HEAD + r16;
    cr[ 0] = cc0[i] * inv4[i];
    cr[16] = cc1[i] * inv4[i];
    cr[32] = cc2[i] * inv4[i];
    cr[48] = cc3[i] * inv4[i];
  }
}

extern "C" void kernel_launch(void* const* d_in, const int* in_sizes, int n_in,
                              void* d_out, int out_size, void* d_ws, size_t ws_size,
                              hipStream_t stream) {
  const float* Q = (const float*)d_in[0];
  const float* K = (const float*)d_in[1];
  const float* V = (const float*)d_in[2];
  const void*  M = d_in[3];

  float* ctx  = (float*)d_out;
  float* prob = (float*)d_out + (size_t)NBH * S_LEN * D_HEAD;

  // ws: [0,4) flag | [2MB,10MB) Kb | [10MB,18MB) Vt
  int*   flag = (int*)d_ws;
  unsigned short* Kb = (unsigned short*)((char*)d_ws + (2u << 20));
  unsigned short* Vt = (unsigned short*)((char*)d_ws + (10u << 20));

  hipLaunchKernelGGL(detect_mask_kernel, dim3(1), dim3(256), 0, stream,
                     (const unsigned int*)M, flag);
  hipLaunchKernelGGL(convK_kernel, dim3(2048), dim3(256), 0, stream, K, Kb);
  hipLaunchKernelGGL(vtrans_kernel, dim3(S_LEN/32, NBH), dim3(256), 0, stream, V, Vt);
  hipLaunchKernelGGL(attn_kernel, dim3(S_LEN/64, NBH), dim3(256), 0, stream,
                     Q, Kb, M, flag, Vt, prob, ctx);
}

// Round 3
// 1147.900 us; speedup vs baseline: 1.1199x; 1.1199x over previous
//
#include <hip/hip_runtime.h>
#include <cstdint>
#include <cstddef>

// B=2, H=16, S=2048, D=64. fp32 inputs (Q,K,V), mask (int32/uint8 auto-detected),
// fp32 outputs: [context | attn_prob] concatenated.
//
// v3: v1 single-pass structure + BIT-PACKED MASK.
//  - packmask_kernel: mask (134MB u8 / 537MB i32) -> 1 bit/elem (16.8MB),
//    stored IN THE ctx OUTPUT REGION (identical 256B/row stride; each wave
//    reads exactly the pm words it later overwrites with ctx -> no hazard).
//  - phase 1: mask = 4x ui4 loads per 32 iters (L2/L3-resident), prefetched;
//    K-loop unrolled 8 for MLP. This removes the cold-HBM 4B/iter mask
//    stream that was the latency bottleneck (v0-v2 all ~latency-bound,
//    occupancy doubling in v2 didn't help).
//  - phase 3: dual accumulators + unroll 8 (breaks serial MFMA chain).
#define S_LEN 2048
#define D_HEAD 64
#define NBH 32

typedef __attribute__((ext_vector_type(8))) short short8;
typedef __attribute__((ext_vector_type(8))) unsigned short ushort8;
typedef __attribute__((ext_vector_type(4))) unsigned short us4;
typedef __attribute__((ext_vector_type(4))) unsigned int ui4;
typedef __attribute__((ext_vector_type(4))) float floatx4;

__device__ __forceinline__ unsigned short f2bf(float f){
  union { float f; unsigned int i; } v; v.f = f;
  unsigned int u = v.i;
  u += 0x7fffu + ((u >> 16) & 1u);     // RNE
  return (unsigned short)(u >> 16);
}
__device__ __forceinline__ float bf2f(unsigned short u){
  union { unsigned int i; float f; } v; v.i = ((unsigned int)u) << 16; return v.f;
}

// XOR swizzle at 16B granularity, 4-bit (16-slot) spread. P tile stays 64KB.
__device__ __forceinline__ int swz(int row, int col){
  return row * S_LEN + ((((col >> 3) ^ row) & 15) << 3)
                     + (((col >> 3) & ~15) << 3) + (col & 7);
}

// ---- mask width detect: int32 0/1 -> every 4B word <= 1; uint8 0/1 -> words >1 whp.
__global__ void detect_mask_kernel(const unsigned int* __restrict__ m, int* __restrict__ flag){
  __shared__ int f;
  if (threadIdx.x == 0) f = 0;
  __syncthreads();
  if (m[threadIdx.x] > 1u) atomicOr(&f, 1);
  __syncthreads();
  if (threadIdx.x == 0) *flag = f;   // 0 = int32, 1 = uint8
}

// ---- mask -> 1 bit/element. Word w holds cols [32w, 32w+32) of the flattened
// [BH*S, S] mask; bit j = col 32w+j. One thread = one output word.
__global__ void packmask_kernel(const void* __restrict__ maskp, const int* __restrict__ flag,
                                unsigned int* __restrict__ pm){
  const int w = blockIdx.x * 256 + threadIdx.x;
  unsigned int bits = 0;
  if (*flag){   // uint8
    const unsigned char* mb = (const unsigned char*)maskp + (size_t)w * 32;
    const ui4 x0 = *(const ui4*)(mb);
    const ui4 x1 = *(const ui4*)(mb + 16);
#pragma unroll
    for (int i = 0; i < 4; ++i){
      const unsigned int a = x0[i], b = x1[i];
#pragma unroll
      for (int j = 0; j < 4; ++j){
        bits |= (((a >> (8 * j)) & 0xffu) ? 1u : 0u) << (4 * i + j);
        bits |= (((b >> (8 * j)) & 0xffu) ? 1u : 0u) << (16 + 4 * i + j);
      }
    }
  } else {      // int32
    const unsigned int* mi = (const unsigned int*)maskp + (size_t)w * 32;
#pragma unroll
    for (int i = 0; i < 8; ++i){
      const ui4 x = *(const ui4*)(mi + i * 4);
#pragma unroll
      for (int j = 0; j < 4; ++j)
        bits |= (x[j] ? 1u : 0u) << (i * 4 + j);
    }
  }
  pm[w] = bits;
}

// ---- K fp32 -> Kb bf16 (same layout). 8 elems/thread.
__global__ void convK_kernel(const float* __restrict__ K, unsigned short* __restrict__ Kb){
  const size_t i = ((size_t)blockIdx.x * 256 + threadIdx.x) * 8;
  floatx4 x0 = *(const floatx4*)(K + i);
  floatx4 x1 = *(const floatx4*)(K + i + 4);
  ushort8 o;
#pragma unroll
  for (int j = 0; j < 4; ++j){ o[j] = f2bf(x0[j]); o[4 + j] = f2bf(x1[j]); }
  *(ushort8*)(Kb + i) = o;
}

// ---- V fp32 -> Vt bf16 transposed: Vt[bh][n][k] (k contiguous for PV B-frags).
__global__ void vtrans_kernel(const float* __restrict__ V, unsigned short* __restrict__ Vt){
  const int bh = blockIdx.y;
  const int n  = threadIdx.x & 63;
  const int k0 = blockIdx.x * 32 + (threadIdx.x >> 6) * 8;
  const float* Vp = V + (size_t)bh * S_LEN * D_HEAD;
  ushort8 o;
#pragma unroll
  for (int i = 0; i < 8; ++i) o[i] = f2bf(Vp[(size_t)(k0 + i) * D_HEAD + n]);
  *(ushort8*)(Vt + (size_t)bh * D_HEAD * S_LEN + (size_t)n * S_LEN + k0) = o;
}

// ---- fused attention: per block = 16 q-rows x full S.
// SWAPPED QK^T: c = mfma(K_frag, Q_frag) -> C col=lane&15 = q-row,
// row=quad*4+reg = score-col (verified r1/r2). Lane (r16,quad) owns q-row r16,
// score-cols {16t + quad*4 + i}.
__global__ __launch_bounds__(256, 2) void attn_kernel(
    const float* __restrict__ Q, const unsigned short* __restrict__ Kb,
    const unsigned int* __restrict__ pm,
    const unsigned short* __restrict__ Vt,
    float* __restrict__ prob, float* __restrict__ ctx,
    float* __restrict__ redg, float* __restrict__ invg){

  __shared__ unsigned short Pt[16 * S_LEN];   // exactly 64 KB

  // XCD-aware remap: 4096 blocks = 8 XCD x (4 heads x 128 qt).
  const int lin  = blockIdx.y * gridDim.x + blockIdx.x;
  const int xcd  = lin & 7;
  const int sub  = lin >> 3;
  const int bh   = xcd * 4 + (sub & 3);
  const int qt   = sub >> 2;

  const int q0g  = bh * S_LEN + qt * 16;      // row index into flattened [BH*S]
  const int tid  = threadIdx.x;
  const int wave = tid >> 6;
  const int lane = tid & 63;
  const int quad = lane >> 4;
  const int r16  = lane & 15;
  const int blk  = bh * gridDim.x + qt;

  // ---- Phase 1 ----
  const float* qrow = Q + (size_t)(q0g + r16) * D_HEAD + quad * 8;
  short8 a0, a1;
  {
    floatx4 x0 = *(const floatx4*)(qrow);
    floatx4 x1 = *(const floatx4*)(qrow + 4);
    floatx4 y0 = *(const floatx4*)(qrow + 32);
    floatx4 y1 = *(const floatx4*)(qrow + 36);
#pragma unroll
    for (int j = 0; j < 4; ++j){
      a0[j] = (short)f2bf(x0[j]); a0[4 + j] = (short)f2bf(x1[j]);
      a1[j] = (short)f2bf(y0[j]); a1[4 + j] = (short)f2bf(y1[j]);
    }
  }

  // packed mask: row (q0g+r16) has 64 words; this wave's strip = words [wave*16, +16)
  const unsigned int* mrow = pm + (size_t)(q0g + r16) * 64 + wave * 16;
  const unsigned short* kbase = Kb + (size_t)bh * S_LEN * D_HEAD;

  float racc = 0.f;
  ui4 mcur = *(const ui4*)(mrow);
  for (int tt = 0; tt < 4; ++tt){
    const ui4 mnext = (tt < 3) ? *(const ui4*)(mrow + (tt + 1) * 4) : mcur;
#pragma unroll
    for (int tj = 0; tj < 8; ++tj){
      const int t  = tt * 8 + tj;
      const int s0 = wave * 512 + t * 16;
      const unsigned short* krow = kbase + (size_t)(s0 + r16) * D_HEAD + quad * 8;
      const short8 b0 = *(const short8*)(krow);
      const short8 b1 = *(const short8*)(krow + 32);
      floatx4 c = {0.f, 0.f, 0.f, 0.f};
      c = __builtin_amdgcn_mfma_f32_16x16x32_bf16(b0, a0, c, 0, 0, 0);  // swapped
      c = __builtin_amdgcn_mfma_f32_16x16x32_bf16(b1, a1, c, 0, 0, 0);
      const unsigned int bits = mcur[tj >> 1] >> (16 * (tj & 1) + 4 * quad);
      us4 w;
#pragma unroll
      for (int i = 0; i < 4; ++i){
        const float p = ((bits >> i) & 1u) ? 0.0f : __expf(c[i] * 0.125f);
        racc += p;
        w[i] = f2bf(p);
      }
      *(us4*)(&Pt[swz(r16, s0 + quad * 4)]) = w;
    }
    mcur = mnext;
  }

  // ---- Phase 2: rowsums (quads hold disjoint col-chunks of row r16) ----
  racc += __shfl_xor(racc, 16);
  racc += __shfl_xor(racc, 32);
  if (lane < 16) redg[(size_t)blk * 64 + wave * 16 + lane] = racc;
  __syncthreads();   // P tile complete + partials visible
  if (tid < 16){
    float s = 0.f;
#pragma unroll
    for (int w = 0; w < 4; ++w) s += redg[(size_t)blk * 64 + w * 16 + tid];
    invg[(size_t)blk * 16 + tid] = (s > 0.f) ? (1.0f / s) : 0.0f;
  }
  __syncthreads();

  // ---- Phase 3: PV. wave w -> ctx cols [16w, 16w+16) ----
  float inv4[4];
#pragma unroll
  for (int i = 0; i < 4; ++i) inv4[i] = invg[(size_t)blk * 16 + quad * 4 + i];

  const unsigned short* vrow = Vt + (size_t)bh * D_HEAD * S_LEN
                                  + (size_t)(wave * 16 + r16) * S_LEN + quad * 8;
  floatx4 cA = {0.f,0.f,0.f,0.f}, cB = {0.f,0.f,0.f,0.f};
#pragma unroll 8
  for (int kk = 0; kk < 64; kk += 2){
    const short8 bv0 = *(const short8*)(vrow + kk * 32);
    const short8 aa0 = *(const short8*)(&Pt[swz(r16, kk * 32 + quad * 8)]);
    const short8 bv1 = *(const short8*)(vrow + (kk + 1) * 32);
    const short8 aa1 = *(const short8*)(&Pt[swz(r16, (kk + 1) * 32 + quad * 8)]);
    cA = __builtin_amdgcn_mfma_f32_16x16x32_bf16(aa0, bv0, cA, 0, 0, 0);
    cB = __builtin_amdgcn_mfma_f32_16x16x32_bf16(aa1, bv1, cB, 0, 0, 0);
  }
  // ctx overwrites the pm words this wave consumed in phase 1 (exact alias, safe)
#pragma unroll
  for (int i = 0; i < 4; ++i)
    ctx[(size_t)(q0g + quad * 4 + i) * D_HEAD + wave * 16 + r16] = (cA[i] + cB[i]) * inv4[i];

  // ---- Phase 4: normalized prob (no barrier: Pt read-only from here on) ----
#pragma unroll
  for (int rr = 0; rr < 4; ++rr){
    const int row = wave * 4 + rr;
    const float iv = invg[(size_t)blk * 16 + row];
    float* pg = prob + (size_t)(q0g + row) * S_LEN;
#pragma unroll
    for (int j = 0; j < 4; ++j){
      const int col = j * 512 + lane * 8;
      const ushort8 u = *(const ushort8*)(&Pt[swz(row, col)]);  // b128
      floatx4 o0, o1;
#pragma unroll
      for (int e = 0; e < 4; ++e){
        o0[e] = bf2f(u[e]) * iv;
        o1[e] = bf2f(u[4 + e]) * iv;
      }
      *(floatx4*)(pg + col)     = o0;
      *(floatx4*)(pg + col + 4) = o1;
    }
  }
}

extern "C" void kernel_launch(void* const* d_in, const int* in_sizes, int n_in,
                              void* d_out, int out_size, void* d_ws, size_t ws_size,
                              hipStream_t stream) {
  const float* Q = (const float*)d_in[0];
  const float* K = (const float*)d_in[1];
  const float* V = (const float*)d_in[2];
  const void*  M = d_in[3];

  float* ctx  = (float*)d_out;
  float* prob = (float*)d_out + (size_t)NBH * S_LEN * D_HEAD;

  // packed mask lives in the ctx output region: 32*2048 rows x 64 words x 4B
  // = 16.78MB = exactly sizeof(ctx); identical 256B row stride. Each attn wave
  // reads only the pm words it later overwrites with its own ctx values.
  unsigned int* pm = (unsigned int*)d_out;

  // ws: [0,4) flag | [4KB, +1MB) redg | [+1MB, +256KB) invg | [2MB,10MB) Kb | [10MB,18MB) Vt
  int*   flag = (int*)d_ws;
  float* redg = (float*)((char*)d_ws + (1u << 12));
  float* invg = (float*)((char*)d_ws + (1u << 12) + (1u << 20));
  unsigned short* Kb = (unsigned short*)((char*)d_ws + (2u << 20));
  unsigned short* Vt = (unsigned short*)((char*)d_ws + (10u << 20));

  hipLaunchKernelGGL(detect_mask_kernel, dim3(1), dim3(256), 0, stream,
                     (const unsigned int*)M, flag);
  hipLaunchKernelGGL(packmask_kernel, dim3((NBH * S_LEN * S_LEN / 32) / 256), dim3(256),
                     0, stream, M, flag, pm);
  hipLaunchKernelGGL(convK_kernel, dim3(2048), dim3(256), 0, stream, K, Kb);
  hipLaunchKernelGGL(vtrans_kernel, dim3(S_LEN/32, NBH), dim3(256), 0, stream, V, Vt);
  hipLaunchKernelGGL(attn_kernel, dim3(S_LEN/16, NBH), dim3(256), 0, stream,
                     Q, Kb, pm, Vt, prob, ctx, redg, invg);
}